// Round 14
// baseline (752.225 us; speedup 1.0000x reference)
//
#include <hip/hip_runtime.h>
#include <cstdint>
#include <math.h>
#include <float.h>

// Problem constants
#define N_Q   4
#define NROWS 32768
#define EDIM  256
#define NE    2048
#define NCT   64           // code tiles per half (16 codes each)
#define TM    64           // rows per block; grid 512 -> 2 blocks/CU
#define NTHREADS 256

// Output layout: z_q | loss | indices (fp32)
#define ZQ_SIZE  (NROWS * EDIM)
#define LOSS_OFF ZQ_SIZE
#define IDX_OFF  (ZQ_SIZE + 1)

// Single fp16xfp16 product screen (validated R5-R8/R10-R13): sigma_dist ~ 6.4e-4,
// TAU/2 = 6e-3 ~ 9.4 sigma. Screen folds d' = wq - 2G (NO S term): S is
// constant per row, so gaps m2-m1 / m3-m1 are exactly S-invariant. RECHECKS
// use the numpy chain verbatim (np_block128_sq Srow + sequential-fmaf dot) —
// the proven zero-flip recipe (R0-R8, R10-R13).
// Tiers: m2-m1 > TAU -> certified; else m3-m1 > TAU -> exact 2-cand recheck;
// else full 2048-code exact recheck.
#define TAU 0.012f

typedef __attribute__((ext_vector_type(8))) _Float16 f16x8;
typedef __attribute__((ext_vector_type(4))) float    f32x4;

union F8 { _Float16 h[8]; f16x8 v; };

// ---- numpy pairwise fp32 sum-of-squares emulation (128-float block) ----
__device__ __forceinline__ float np_block128_sq(const float* __restrict__ p) {
    #pragma clang fp contract(off)
    float r[8];
    #pragma unroll
    for (int j = 0; j < 8; ++j) { float v = p[j]; r[j] = v * v; }
    for (int i = 8; i < 128; i += 8) {
        #pragma unroll
        for (int j = 0; j < 8; ++j) { float v = p[i + j]; float sq = v * v; r[j] = r[j] + sq; }
    }
    return ((r[0] + r[1]) + (r[2] + r[3])) + ((r[4] + r[5]) + (r[6] + r[7]));
}

__global__ __launch_bounds__(256) void wsq_kernel(const float* __restrict__ W,
                                                  float* __restrict__ wsq32) {
    __shared__ float rowbuf[4][EDIM];
    int wv   = threadIdx.x >> 6;
    int row  = blockIdx.x * 4 + (threadIdx.x >> 6);
    int lane = threadIdx.x & 63;
    float4 v = ((const float4*)(W + (size_t)row * EDIM))[lane];
    *(float4*)&rowbuf[wv][lane * 4] = v;
    __syncthreads();
    if (lane == 0) {
        float a = np_block128_sq(rowbuf[wv]);
        float b = np_block128_sq(rowbuf[wv] + 128);
        wsq32[row] = a + b;
    }
}

// Pre-convert W to fp16, swizzled into MFMA B-frag blocks:
// grp = (q*128 + ct_global)*8 + ks ; block of 512 shorts at grp<<9
// value = fp16( W[q][ct_global*16 + (lane&15)][ks*32 + (lane>>4)*8 + j] )
__global__ __launch_bounds__(256) void wh_kernel(const float* __restrict__ W,
                                                 short* __restrict__ wh) {
    int gid  = blockIdx.x * 256 + threadIdx.x;
    int lane = gid & 63;
    int grp  = gid >> 6;                 // 4096 total
    int ctq  = grp >> 3;
    int ks   = grp & 7;
    int n = lane & 15, kq = lane >> 4;
    const float* src = W + (((size_t)(ctq * 16 + n)) << 8) + ks * 32 + kq * 8;
    float4 p0 = *(const float4*)src;
    float4 p1 = *(const float4*)(src + 4);
    float v[8] = {p0.x, p0.y, p0.z, p0.w, p1.x, p1.y, p1.z, p1.w};
    F8 h;
    #pragma unroll
    for (int j = 0; j < 8; ++j) h.h[j] = (_Float16)v[j];
    *(f16x8*)(wh + (((size_t)grp) << 9) + lane * 8) = h.v;
}

// merge two sorted top-3 sets (values asc, indices for top-2); ties -> lower index
__device__ __forceinline__ void top3_merge(float& a1, int& ai1, float& a2, int& ai2, float& a3,
                                           float b1, int bi1, float b2, int bi2, float b3) {
    float c1, c2, c3; int k1, k2;
    if (b1 < a1 || (b1 == a1 && bi1 < ai1)) {
        c1 = b1; k1 = bi1;
        if (a1 < b2 || (a1 == b2 && ai1 < bi2)) { c2 = a1; k2 = ai1; c3 = fminf(b2, a2); }
        else                                    { c2 = b2; k2 = bi2; c3 = fminf(a1, b3); }
    } else {
        c1 = a1; k1 = ai1;
        if (b1 < a2 || (b1 == a2 && bi1 < ai2)) { c2 = b1; k2 = bi1; c3 = fminf(a2, b2); }
        else                                    { c2 = a2; k2 = ai2; c3 = fminf(b1, a3); }
    }
    a1 = c1; ai1 = k1; a2 = c2; ai2 = k2; a3 = c3;
}

__global__ __launch_bounds__(256, 2) void rvq_main(
    const float* __restrict__ z, const float* __restrict__ W,
    const float* __restrict__ wsq32, const short* __restrict__ wh,
    float* __restrict__ resd_g, float* __restrict__ out,
    float* __restrict__ loss_partial)
{
    // 64 KB wave-PRIVATE staging rings: [wave][ring-buf][ksl][512 shorts]
    // (no cross-wave LDS hazard in the hot loop -> zero hot-loop barriers)
    __shared__ __align__(16) short lds_b[4][4][4][512];
    __shared__ float wsq_lds[2048];      // per-q ||W||^2 (8 KB)
    __shared__ float Srow[TM];           // np-chain S (recheck grid)
    __shared__ float rm1[2][TM], rm2[2][TM], rm3[2][TM];
    __shared__ int   ri1[2][TM], ri2[2][TM];
    __shared__ int   idx_s[TM], is2_s[TM];
    __shared__ int   rk_cnt, rk_list[TM];
    __shared__ int   pr_cnt, pr_list[TM];
    __shared__ float wavesum[4];

    // recheck scratch aliases the (dead-outside-hot-loop) ring memory
    float* rrow_s = (float*)&lds_b[0][0][0][0];   // 1 KB
    float* red_f  = (float*)&lds_b[1][0][0][0];   // 1 KB
    int*   red_i  = (int*)  &lds_b[1][1][0][0];   // 1 KB

    const int tid  = threadIdx.x;
    const int wave = tid >> 6;
    const int lane = tid & 63;
    const int n    = lane & 15;
    const int kq   = lane >> 4;
    const int chalf = wave & 1;      // code half (0: codes 0..1023, 1: 1024..2047)
    const int rsel  = wave >> 1;     // row half (0: rows 0..31, 1: 32..63)
    const int row0 = blockIdx.x * TM;
    const int rowg = row0 + rsel * 32;

    // init: copy z -> residual (own rows only)
    for (int i = tid; i < TM * 64; i += NTHREADS) {
        int r = i >> 6, c = i & 63;
        ((float4*)resd_g)[(((size_t)(row0 + r)) << 6) + c] =
            ((const float4*)z)[(((size_t)(row0 + r)) << 6) + c];
    }

    float lsum = 0.f;

    for (int q = 0; q < N_Q; ++q) {
        const float* Wk   = W + (size_t)q * NE * EDIM;
        const float* wsqk = wsq32 + q * NE;
        const short* whq  = wh + ((size_t)q << 19);   // q * 1024*512 shorts

        __syncthreads();   // residual stable; ring/aliases free
        if (tid == 0) { rk_cnt = 0; pr_cnt = 0; }
        if (tid < 2 * TM) {   // np-chain Srow (for rechecks)
            int r = tid >> 1, hf = tid & 1;
            float s = np_block128_sq(resd_g + (((size_t)(row0 + r)) << 8) + hf * 128);
            float s2 = __shfl_xor(s, 1, 64);
            if (hf == 0) Srow[r] = s + s2;
        }
        // wsq -> LDS (keeps hot loop vmcnt-clean: wq reads become lgkmcnt)
        for (int i = tid; i < 512; i += NTHREADS)
            ((float4*)wsq_lds)[i] = ((const float4*)wsqk)[i];

        // ---- A-frag conversion: 32 rows/wave (2 tiles), 8 k-steps, fp16 ----
        f16x8 ah[2][8];
        #pragma unroll
        for (int t = 0; t < 2; ++t) {
            #pragma unroll
            for (int ks = 0; ks < 8; ++ks) {
                const float* rp = resd_g + (((size_t)(rowg + t * 16 + n)) << 8) + ks * 32 + kq * 8;
                float4 p0 = *(const float4*)rp;
                float4 p1 = *(const float4*)(rp + 4);
                float v[8] = {p0.x, p0.y, p0.z, p0.w, p1.x, p1.y, p1.z, p1.w};
                F8 h;
                #pragma unroll
                for (int j = 0; j < 8; ++j) h.h[j] = (_Float16)v[j];
                ah[t][ks] = h.v;
            }
        }
        __syncthreads();   // Srow + wsq_lds visible to all

        float M1[8], M2[8], M3[8]; int I1[8], I2[8];
        #pragma unroll
        for (int s = 0; s < 8; ++s) {
            M1[s] = INFINITY; M2[s] = INFINITY; M3[s] = INFINITY; I1[s] = 0; I2[s] = 0;
        }

        // private staging: phase p = ct*2+kp -> ring buf p&3 (own copy, 4 chunks)
        auto stage = [&](int p) {
            int ct = p >> 1, kp = p & 1;
            int b = p & 3;
            #pragma unroll
            for (int ksl = 0; ksl < 4; ++ksl) {
                size_t grp = ((size_t)(chalf * 64 + ct) << 3) + kp * 4 + ksl;
                const short* gp = whq + (grp << 9) + lane * 8;
                __builtin_amdgcn_global_load_lds(
                    (const __attribute__((address_space(1))) void*)gp,
                    (__attribute__((address_space(3))) void*)&lds_b[wave][b][ksl][0],
                    16, 0, 0);
            }
        };

        // compute ct into the given acc set (4 independent MFMA chains);
        // staging cadence and waits identical to R11.
        auto computeCT = [&](int ct, f32x4 (&acc)[2][2], float& wqv) {
            wqv = wsq_lds[chalf * 1024 + ct * 16 + n];
            // phase A (p = 2ct)
            asm volatile("s_waitcnt vmcnt(4)" ::: "memory");
            __builtin_amdgcn_sched_barrier(0);
            {
                const int b = (2 * ct) & 3;
                acc[0][0] = (f32x4){0.f, 0.f, 0.f, 0.f};
                acc[0][1] = (f32x4){0.f, 0.f, 0.f, 0.f};
                acc[1][0] = (f32x4){0.f, 0.f, 0.f, 0.f};
                acc[1][1] = (f32x4){0.f, 0.f, 0.f, 0.f};
                #pragma unroll
                for (int ksl = 0; ksl < 4; ++ksl) {
                    f16x8 bh = *(const f16x8*)&lds_b[wave][b][ksl][lane * 8];
                    const int c = ksl & 1;
                    acc[0][c] = __builtin_amdgcn_mfma_f32_16x16x32_f16(ah[0][ksl], bh, acc[0][c], 0, 0, 0);
                    acc[1][c] = __builtin_amdgcn_mfma_f32_16x16x32_f16(ah[1][ksl], bh, acc[1][c], 0, 0, 0);
                }
            }
            if (2 * ct + 2 < 2 * NCT) stage(2 * ct + 2);
            // phase B (p = 2ct+1)
            if (ct < NCT - 1) {
                asm volatile("s_waitcnt vmcnt(4)" ::: "memory");
            } else {
                asm volatile("s_waitcnt vmcnt(0)" ::: "memory");
            }
            __builtin_amdgcn_sched_barrier(0);
            {
                const int b = (2 * ct + 1) & 3;
                #pragma unroll
                for (int ksl = 0; ksl < 4; ++ksl) {
                    f16x8 bh = *(const f16x8*)&lds_b[wave][b][ksl][lane * 8];
                    const int ks = 4 + ksl, c = ksl & 1;
                    acc[0][c] = __builtin_amdgcn_mfma_f32_16x16x32_f16(ah[0][ks], bh, acc[0][c], 0, 0, 0);
                    acc[1][c] = __builtin_amdgcn_mfma_f32_16x16x32_f16(ah[1][ks], bh, acc[1][c], 0, 0, 0);
                }
            }
            if (2 * ct + 3 < 2 * NCT) stage(2 * ct + 3);
        };

        // fold ct's results: d' = wq - 2G; track top-3 values, top-2 indices
        auto foldCT = [&](const f32x4 (&acc)[2][2], float wqv, int ct) {
            int cg = chalf * 1024 + ct * 16 + n;
            #pragma unroll
            for (int t = 0; t < 2; ++t) {
                #pragma unroll
                for (int rg = 0; rg < 4; ++rg) {
                    float g = acc[t][0][rg] + acc[t][1][rg];
                    float d = fmaf(-2.0f, g, wqv);
                    int s = t * 4 + rg;
                    bool c1 = d < M1[s];
                    bool c2 = d < M2[s];
                    M3[s] = fminf(M3[s], fmaxf(M2[s], d));
                    M2[s] = fminf(M2[s], fmaxf(M1[s], d));
                    I2[s] = c1 ? I1[s] : (c2 ? cg : I2[s]);
                    M1[s] = fminf(M1[s], d);
                    I1[s] = c1 ? cg : I1[s];
                }
            }
        };

        // drain lingering loads/stores so vmcnt counts ONLY ring staging
        asm volatile("s_waitcnt vmcnt(0)" ::: "memory");
        stage(0);
        stage(1);

        // ---- barrier-free hot loop, fold deferred one ct (static ping-pong) ----
        f32x4 accE[2][2], accO[2][2];
        float wqE, wqO;
        computeCT(0, accE, wqE);
        for (int ctp = 0; ctp < 31; ++ctp) {
            computeCT(2 * ctp + 1, accO, wqO);
            foldCT(accE, wqE, 2 * ctp);
            computeCT(2 * ctp + 2, accE, wqE);
            foldCT(accO, wqO, 2 * ctp + 1);
        }
        computeCT(63, accO, wqO);
        foldCT(accE, wqE, 62);
        foldCT(accO, wqO, 63);

        // ---- reduce top-3 over the 16 n-lanes ----
        #pragma unroll
        for (int s = 0; s < 8; ++s) {
            float a1 = M1[s], a2 = M2[s], a3 = M3[s]; int ai = I1[s], aj = I2[s];
            #pragma unroll
            for (int mask = 1; mask < 16; mask <<= 1) {
                float b1 = __shfl_xor(a1, mask, 64);
                float b2 = __shfl_xor(a2, mask, 64);
                float b3 = __shfl_xor(a3, mask, 64);
                int   bi = __shfl_xor(ai, mask, 64);
                int   bj = __shfl_xor(aj, mask, 64);
                top3_merge(a1, ai, a2, aj, a3, b1, bi, b2, bj, b3);
            }
            if (n == 0) {
                int rr = rsel * 32 + (s >> 2) * 16 + kq * 4 + (s & 3);
                rm1[chalf][rr] = a1; rm2[chalf][rr] = a2; rm3[chalf][rr] = a3;
                ri1[chalf][rr] = ai; ri2[chalf][rr] = aj;
            }
        }
        __syncthreads();

        // ---- merge halves; classify rows by certification tier ----
        if (tid < TM) {
            float a1 = rm1[0][tid], a2 = rm2[0][tid], a3 = rm3[0][tid];
            int ai = ri1[0][tid], aj = ri2[0][tid];
            top3_merge(a1, ai, a2, aj, a3,
                       rm1[1][tid], ri1[1][tid], rm2[1][tid], ri2[1][tid], rm3[1][tid]);
            idx_s[tid] = ai; is2_s[tid] = aj;
            if (a2 - a1 <= TAU) {
                if (a3 - a1 > TAU) { int p = atomicAdd(&pr_cnt, 1); pr_list[p] = tid; }
                else               { int p = atomicAdd(&rk_cnt, 1); rk_list[p] = tid; }
            }
        }
        __syncthreads();

        // ---- exact numpy-chain full recheck (very rare: m3 within TAU) ----
        {
            int ncheck = rk_cnt;
            for (int f = 0; f < ncheck; ++f) {
                int r = rk_list[f];
                if (tid < 64)
                    ((float4*)rrow_s)[tid] =
                        ((const float4*)(resd_g + (((size_t)(row0 + r)) << 8)))[tid];
                __syncthreads();
                float Sr = Srow[r];
                float accv[8];
                #pragma unroll
                for (int j = 0; j < 8; ++j) accv[j] = 0.f;
                const float* wp = Wk + ((size_t)tid * 8) * EDIM;
                for (int kb = 0; kb < 64; ++kb) {
                    float4 rv = *(const float4*)&rrow_s[kb * 4];
                    #pragma unroll
                    for (int j = 0; j < 8; ++j) {
                        float4 wv = *(const float4*)(wp + j * EDIM + kb * 4);
                        accv[j] = fmaf(rv.x, wv.x, accv[j]);
                        accv[j] = fmaf(rv.y, wv.y, accv[j]);
                        accv[j] = fmaf(rv.z, wv.z, accv[j]);
                        accv[j] = fmaf(rv.w, wv.w, accv[j]);
                    }
                }
                float bm = FLT_MAX; int bi = 0;
                #pragma unroll
                for (int j = 0; j < 8; ++j) {
                    int c = tid * 8 + j;
                    float d = fmaf(-2.0f, accv[j], Sr) + wsqk[c];
                    if (d < bm) { bm = d; bi = c; }
                }
                red_f[tid] = bm; red_i[tid] = bi;
                __syncthreads();
                for (int off = 128; off > 0; off >>= 1) {
                    if (tid < off) {
                        float v = red_f[tid + off]; int ii = red_i[tid + off];
                        if (v < red_f[tid] || (v == red_f[tid] && ii < red_i[tid])) {
                            red_f[tid] = v; red_i[tid] = ii;
                        }
                    }
                    __syncthreads();
                }
                if (tid == 0) idx_s[r] = red_i[0];
                __syncthreads();
            }
        }

        // ---- exact 2-candidate recheck (all threads; np-chain; tie -> lower idx) ----
        {
            int cnt2 = pr_cnt * 2;
            for (int base = 0; base < cnt2; base += NTHREADS) {
                int slot = base + tid;
                float d = FLT_MAX; int code = 0; int r = -1;
                if (slot < cnt2) {
                    r = pr_list[slot >> 1];
                    code = (slot & 1) ? is2_s[r] : idx_s[r];
                    const float* rp = resd_g + (((size_t)(row0 + r)) << 8);
                    const float* wp = Wk + ((size_t)code << 8);
                    float acc1 = 0.f;
                    for (int kb = 0; kb < 64; ++kb) {
                        float4 rv = *(const float4*)(rp + kb * 4);
                        float4 wv = *(const float4*)(wp + kb * 4);
                        acc1 = fmaf(rv.x, wv.x, acc1);
                        acc1 = fmaf(rv.y, wv.y, acc1);
                        acc1 = fmaf(rv.z, wv.z, acc1);
                        acc1 = fmaf(rv.w, wv.w, acc1);
                    }
                    d = fmaf(-2.0f, acc1, Srow[r]) + wsqk[code];
                }
                float dp = __shfl_xor(d, 1, 64);
                int   cp = __shfl_xor(code, 1, 64);
                if (slot < cnt2 && (slot & 1) == 0) {
                    idx_s[r] = (dp < d || (dp == d && cp < code)) ? cp : code;
                }
            }
        }
        __syncthreads();

        if (tid < TM)
            out[IDX_OFF + (size_t)(row0 + tid) * N_Q + q] = (float)idx_s[tid];
        __syncthreads();

        // ---- residual update (plain fp32 sub, numpy elementwise) + loss ----
        {
            const int d = tid;
            for (int r = 0; r < TM; ++r) {
                float w = Wk[(((size_t)idx_s[r]) << 8) + d];
                float* rp = resd_g + (((size_t)(row0 + r)) << 8) + d;
                float nv = *rp - w;
                *rp = nv;
                lsum = fmaf(nv, nv, lsum);
            }
        }
    }

    __syncthreads();
    // z_q = z - residual_final
    for (int i = tid; i < TM * 64; i += NTHREADS) {
        int r = i >> 6, c = i & 63;
        float4 zv = ((const float4*)z)[(((size_t)(row0 + r)) << 6) + c];
        float4 rv = ((const float4*)resd_g)[(((size_t)(row0 + r)) << 6) + c];
        float4 o = {zv.x - rv.x, zv.y - rv.y, zv.z - rv.z, zv.w - rv.w};
        ((float4*)out)[(((size_t)(row0 + r)) << 6) + c] = o;
    }
    #pragma unroll
    for (int off = 32; off > 0; off >>= 1) lsum += __shfl_down(lsum, off, 64);
    if (lane == 0) wavesum[wave] = lsum;
    __syncthreads();
    if (tid == 0)
        loss_partial[blockIdx.x] = wavesum[0] + wavesum[1] + wavesum[2] + wavesum[3];
}

__global__ __launch_bounds__(256) void loss_reduce(const float* __restrict__ partial,
                                                   float* __restrict__ out) {
    __shared__ float sh[256];
    int t = threadIdx.x;
    sh[t] = partial[t] + partial[t + 256];
    __syncthreads();
    for (int off = 128; off > 0; off >>= 1) {
        if (t < off) sh[t] += sh[t + off];
        __syncthreads();
    }
    if (t == 0)
        out[LOSS_OFF] = sh[0] * (1.25f / ((float)N_Q * (float)NROWS * (float)EDIM));
}

extern "C" void kernel_launch(void* const* d_in, const int* in_sizes, int n_in,
                              void* d_out, int out_size, void* d_ws, size_t ws_size,
                              hipStream_t stream) {
    const float* z = (const float*)d_in[0];   // [16,2048,256]
    const float* W = (const float*)d_in[1];   // [4,2048,256]
    float* out = (float*)d_out;

    // ws layout (bytes): wsq32 [0,32K) | partial [32K,34K) | wh [64K, 64K+4M) | resd [64K+8M, +32M)
    float* wsq32   = (float*)d_ws;
    float* partial = (float*)((char*)d_ws + 32768);
    short* wh      = (short*)((char*)d_ws + 65536);
    float* resd    = (float*)((char*)d_ws + 65536 + 8388608);

    hipLaunchKernelGGL(wsq_kernel, dim3(NE * N_Q / 4), dim3(NTHREADS), 0, stream, W, wsq32);
    hipLaunchKernelGGL(wh_kernel, dim3(1024), dim3(NTHREADS), 0, stream, W, wh);
    hipLaunchKernelGGL(rvq_main, dim3(NROWS / TM), dim3(NTHREADS), 0, stream,
                       z, W, wsq32, wh, resd, out, partial);
    hipLaunchKernelGGL(loss_reduce, dim3(1), dim3(NTHREADS), 0, stream, partial, out);
}

// Round 16
// 585.868 us; speedup vs baseline: 1.2839x; 1.2839x over previous
//
#include <hip/hip_runtime.h>
#include <cstdint>
#include <math.h>
#include <float.h>

// Problem constants
#define N_Q   4
#define NROWS 32768
#define EDIM  256
#define NE    2048
#define NCT   64           // code tiles per half (16 codes each)
#define TM    64           // rows per block; grid 512 -> 2 blocks/CU
#define NTHREADS 256

// Output layout: z_q | loss | indices (fp32)
#define ZQ_SIZE  (NROWS * EDIM)
#define LOSS_OFF ZQ_SIZE
#define IDX_OFF  (ZQ_SIZE + 1)

// Single fp16xfp16 product screen (validated R5-R8/R10-R14): sigma_dist ~ 6.4e-4,
// TAU/2 = 6e-3 ~ 9.4 sigma. Screen folds d' = wq - 2G (NO S term): S is
// constant per row, so gaps m2-m1 / m3-m1 are exactly S-invariant. RECHECKS
// use the numpy chain verbatim (np_block128_sq Srow + sequential-fmaf dot) —
// the proven zero-flip recipe. Fold top-3 update uses v_med3_f32:
//   fminf(M3,fmaxf(M2,d)) == med3(M2,M3,d), fminf(M2,fmaxf(M1,d)) == med3(M1,M2,d)
// (bit-identical for all orderings; no NaNs; INF-safe).
// Tiers: m2-m1 > TAU -> certified; else m3-m1 > TAU -> exact 2-cand recheck;
// else full 2048-code exact recheck.
#define TAU 0.012f

typedef __attribute__((ext_vector_type(8))) _Float16 f16x8;
typedef __attribute__((ext_vector_type(4))) float    f32x4;

union F8 { _Float16 h[8]; f16x8 v; };

// ---- numpy pairwise fp32 sum-of-squares emulation (128-float block) ----
__device__ __forceinline__ float np_block128_sq(const float* __restrict__ p) {
    #pragma clang fp contract(off)
    float r[8];
    #pragma unroll
    for (int j = 0; j < 8; ++j) { float v = p[j]; r[j] = v * v; }
    for (int i = 8; i < 128; i += 8) {
        #pragma unroll
        for (int j = 0; j < 8; ++j) { float v = p[i + j]; float sq = v * v; r[j] = r[j] + sq; }
    }
    return ((r[0] + r[1]) + (r[2] + r[3])) + ((r[4] + r[5]) + (r[6] + r[7]));
}

__global__ __launch_bounds__(256) void wsq_kernel(const float* __restrict__ W,
                                                  float* __restrict__ wsq32) {
    __shared__ float rowbuf[4][EDIM];
    int wv   = threadIdx.x >> 6;
    int row  = blockIdx.x * 4 + (threadIdx.x >> 6);
    int lane = threadIdx.x & 63;
    float4 v = ((const float4*)(W + (size_t)row * EDIM))[lane];
    *(float4*)&rowbuf[wv][lane * 4] = v;
    __syncthreads();
    if (lane == 0) {
        float a = np_block128_sq(rowbuf[wv]);
        float b = np_block128_sq(rowbuf[wv] + 128);
        wsq32[row] = a + b;
    }
}

// Pre-convert W to fp16, swizzled into MFMA B-frag blocks:
// grp = (q*128 + ct_global)*8 + ks ; block of 512 shorts at grp<<9
// value = fp16( W[q][ct_global*16 + (lane&15)][ks*32 + (lane>>4)*8 + j] )
__global__ __launch_bounds__(256) void wh_kernel(const float* __restrict__ W,
                                                 short* __restrict__ wh) {
    int gid  = blockIdx.x * 256 + threadIdx.x;
    int lane = gid & 63;
    int grp  = gid >> 6;                 // 4096 total
    int ctq  = grp >> 3;
    int ks   = grp & 7;
    int n = lane & 15, kq = lane >> 4;
    const float* src = W + (((size_t)(ctq * 16 + n)) << 8) + ks * 32 + kq * 8;
    float4 p0 = *(const float4*)src;
    float4 p1 = *(const float4*)(src + 4);
    float v[8] = {p0.x, p0.y, p0.z, p0.w, p1.x, p1.y, p1.z, p1.w};
    F8 h;
    #pragma unroll
    for (int j = 0; j < 8; ++j) h.h[j] = (_Float16)v[j];
    *(f16x8*)(wh + (((size_t)grp) << 9) + lane * 8) = h.v;
}

// merge two sorted top-3 sets (values asc, indices for top-2); ties -> lower index
__device__ __forceinline__ void top3_merge(float& a1, int& ai1, float& a2, int& ai2, float& a3,
                                           float b1, int bi1, float b2, int bi2, float b3) {
    float c1, c2, c3; int k1, k2;
    if (b1 < a1 || (b1 == a1 && bi1 < ai1)) {
        c1 = b1; k1 = bi1;
        if (a1 < b2 || (a1 == b2 && ai1 < bi2)) { c2 = a1; k2 = ai1; c3 = fminf(b2, a2); }
        else                                    { c2 = b2; k2 = bi2; c3 = fminf(a1, b3); }
    } else {
        c1 = a1; k1 = ai1;
        if (b1 < a2 || (b1 == a2 && bi1 < ai2)) { c2 = b1; k2 = bi1; c3 = fminf(a2, b2); }
        else                                    { c2 = a2; k2 = ai2; c3 = fminf(b1, a3); }
    }
    a1 = c1; ai1 = k1; a2 = c2; ai2 = k2; a3 = c3;
}

__global__ __launch_bounds__(256, 2) void rvq_main(
    const float* __restrict__ z, const float* __restrict__ W,
    const float* __restrict__ wsq32, const short* __restrict__ wh,
    float* __restrict__ resd_g, float* __restrict__ out,
    float* __restrict__ loss_partial)
{
    // 64 KB wave-PRIVATE staging rings: [wave][ring-buf][ksl][512 shorts]
    // (no cross-wave LDS hazard in the hot loop -> zero hot-loop barriers)
    __shared__ __align__(16) short lds_b[4][4][4][512];
    __shared__ float wsq_lds[2048];      // per-q ||W||^2 (8 KB)
    __shared__ float Srow[TM];           // np-chain S (recheck grid)
    __shared__ float rm1[2][TM], rm2[2][TM], rm3[2][TM];
    __shared__ int   ri1[2][TM], ri2[2][TM];
    __shared__ int   idx_s[TM], is2_s[TM];
    __shared__ int   rk_cnt, rk_list[TM];
    __shared__ int   pr_cnt, pr_list[TM];
    __shared__ float wavesum[4];

    // recheck scratch aliases the (dead-outside-hot-loop) ring memory
    float* rrow_s = (float*)&lds_b[0][0][0][0];   // 1 KB
    float* red_f  = (float*)&lds_b[1][0][0][0];   // 1 KB
    int*   red_i  = (int*)  &lds_b[1][1][0][0];   // 1 KB

    const int tid  = threadIdx.x;
    const int wave = tid >> 6;
    const int lane = tid & 63;
    const int n    = lane & 15;
    const int kq   = lane >> 4;
    const int chalf = wave & 1;      // code half (0: codes 0..1023, 1: 1024..2047)
    const int rsel  = wave >> 1;     // row half (0: rows 0..31, 1: 32..63)
    const int row0 = blockIdx.x * TM;
    const int rowg = row0 + rsel * 32;

    // init: copy z -> residual (own rows only)
    for (int i = tid; i < TM * 64; i += NTHREADS) {
        int r = i >> 6, c = i & 63;
        ((float4*)resd_g)[(((size_t)(row0 + r)) << 6) + c] =
            ((const float4*)z)[(((size_t)(row0 + r)) << 6) + c];
    }

    float lsum = 0.f;

    for (int q = 0; q < N_Q; ++q) {
        const float* Wk   = W + (size_t)q * NE * EDIM;
        const float* wsqk = wsq32 + q * NE;
        const short* whq  = wh + ((size_t)q << 19);   // q * 1024*512 shorts

        __syncthreads();   // residual stable; ring/aliases free
        if (tid == 0) { rk_cnt = 0; pr_cnt = 0; }
        if (tid < 2 * TM) {   // np-chain Srow (for rechecks)
            int r = tid >> 1, hf = tid & 1;
            float s = np_block128_sq(resd_g + (((size_t)(row0 + r)) << 8) + hf * 128);
            float s2 = __shfl_xor(s, 1, 64);
            if (hf == 0) Srow[r] = s + s2;
        }
        // wsq -> LDS (keeps hot loop vmcnt-clean: wq reads become lgkmcnt)
        for (int i = tid; i < 512; i += NTHREADS)
            ((float4*)wsq_lds)[i] = ((const float4*)wsqk)[i];

        // ---- A-frag conversion: 32 rows/wave (2 tiles), 8 k-steps, fp16 ----
        f16x8 ah[2][8];
        #pragma unroll
        for (int t = 0; t < 2; ++t) {
            #pragma unroll
            for (int ks = 0; ks < 8; ++ks) {
                const float* rp = resd_g + (((size_t)(rowg + t * 16 + n)) << 8) + ks * 32 + kq * 8;
                float4 p0 = *(const float4*)rp;
                float4 p1 = *(const float4*)(rp + 4);
                float v[8] = {p0.x, p0.y, p0.z, p0.w, p1.x, p1.y, p1.z, p1.w};
                F8 h;
                #pragma unroll
                for (int j = 0; j < 8; ++j) h.h[j] = (_Float16)v[j];
                ah[t][ks] = h.v;
            }
        }
        __syncthreads();   // Srow + wsq_lds visible to all

        float M1[8], M2[8], M3[8]; int I1[8], I2[8];
        #pragma unroll
        for (int s = 0; s < 8; ++s) {
            M1[s] = INFINITY; M2[s] = INFINITY; M3[s] = INFINITY; I1[s] = 0; I2[s] = 0;
        }

        // private staging: phase p = ct*2+kp -> ring buf p&3 (own copy, 4 chunks)
        auto stage = [&](int p) {
            int ct = p >> 1, kp = p & 1;
            int b = p & 3;
            #pragma unroll
            for (int ksl = 0; ksl < 4; ++ksl) {
                size_t grp = ((size_t)(chalf * 64 + ct) << 3) + kp * 4 + ksl;
                const short* gp = whq + (grp << 9) + lane * 8;
                __builtin_amdgcn_global_load_lds(
                    (const __attribute__((address_space(1))) void*)gp,
                    (__attribute__((address_space(3))) void*)&lds_b[wave][b][ksl][0],
                    16, 0, 0);
            }
        };

        // drain lingering loads/stores so vmcnt counts ONLY ring staging
        asm volatile("s_waitcnt vmcnt(0)" ::: "memory");
        stage(0);
        stage(1);

        f32x4 acc[2];
        // ---- barrier-free hot loop: per-wave counted vmcnt, never a barrier ----
        // steady state: 8 loads in flight (phases p+1, p+2); wait(4) -> phase p landed
        for (int ct = 0; ct < NCT; ++ct) {
            float wq = wsq_lds[chalf * 1024 + ct * 16 + n];

            // phase A (p = 2ct)
            asm volatile("s_waitcnt vmcnt(4)" ::: "memory");
            __builtin_amdgcn_sched_barrier(0);
            {
                const int b = (2 * ct) & 3;
                acc[0] = (f32x4){0.f, 0.f, 0.f, 0.f};
                acc[1] = (f32x4){0.f, 0.f, 0.f, 0.f};
                #pragma unroll
                for (int ksl = 0; ksl < 4; ++ksl) {
                    f16x8 bh = *(const f16x8*)&lds_b[wave][b][ksl][lane * 8];
                    acc[0] = __builtin_amdgcn_mfma_f32_16x16x32_f16(ah[0][ksl], bh, acc[0], 0, 0, 0);
                    acc[1] = __builtin_amdgcn_mfma_f32_16x16x32_f16(ah[1][ksl], bh, acc[1], 0, 0, 0);
                }
            }
            if (ct < NCT - 1) stage(2 * ct + 2);

            // phase B (p = 2ct+1)
            if (ct < NCT - 1) {
                asm volatile("s_waitcnt vmcnt(4)" ::: "memory");
            } else {
                asm volatile("s_waitcnt vmcnt(0)" ::: "memory");
            }
            __builtin_amdgcn_sched_barrier(0);
            {
                const int b = (2 * ct + 1) & 3;
                #pragma unroll
                for (int ksl = 0; ksl < 4; ++ksl) {
                    f16x8 bh = *(const f16x8*)&lds_b[wave][b][ksl][lane * 8];
                    acc[0] = __builtin_amdgcn_mfma_f32_16x16x32_f16(ah[0][4 + ksl], bh, acc[0], 0, 0, 0);
                    acc[1] = __builtin_amdgcn_mfma_f32_16x16x32_f16(ah[1][4 + ksl], bh, acc[1], 0, 0, 0);
                }
            }
            if (ct < NCT - 1) stage(2 * ct + 3);

            // ---- fold: d' = wq - 2G; top-3 via med3 (equiv to min/max pair) ----
            int cg = chalf * 1024 + ct * 16 + n;
            #pragma unroll
            for (int t = 0; t < 2; ++t) {
                #pragma unroll
                for (int rg = 0; rg < 4; ++rg) {
                    float d = fmaf(-2.0f, acc[t][rg], wq);
                    int s = t * 4 + rg;
                    bool c1 = d < M1[s];
                    bool c2 = d < M2[s];
                    M3[s] = __builtin_amdgcn_fmed3f(M2[s], M3[s], d);
                    M2[s] = __builtin_amdgcn_fmed3f(M1[s], M2[s], d);
                    I2[s] = c1 ? I1[s] : (c2 ? cg : I2[s]);
                    M1[s] = fminf(M1[s], d);
                    I1[s] = c1 ? cg : I1[s];
                }
            }
        }

        // ---- reduce top-3 over the 16 n-lanes ----
        #pragma unroll
        for (int s = 0; s < 8; ++s) {
            float a1 = M1[s], a2 = M2[s], a3 = M3[s]; int ai = I1[s], aj = I2[s];
            #pragma unroll
            for (int mask = 1; mask < 16; mask <<= 1) {
                float b1 = __shfl_xor(a1, mask, 64);
                float b2 = __shfl_xor(a2, mask, 64);
                float b3 = __shfl_xor(a3, mask, 64);
                int   bi = __shfl_xor(ai, mask, 64);
                int   bj = __shfl_xor(aj, mask, 64);
                top3_merge(a1, ai, a2, aj, a3, b1, bi, b2, bj, b3);
            }
            if (n == 0) {
                int rr = rsel * 32 + (s >> 2) * 16 + kq * 4 + (s & 3);
                rm1[chalf][rr] = a1; rm2[chalf][rr] = a2; rm3[chalf][rr] = a3;
                ri1[chalf][rr] = ai; ri2[chalf][rr] = aj;
            }
        }
        __syncthreads();

        // ---- merge halves; classify rows by certification tier ----
        if (tid < TM) {
            float a1 = rm1[0][tid], a2 = rm2[0][tid], a3 = rm3[0][tid];
            int ai = ri1[0][tid], aj = ri2[0][tid];
            top3_merge(a1, ai, a2, aj, a3,
                       rm1[1][tid], ri1[1][tid], rm2[1][tid], ri2[1][tid], rm3[1][tid]);
            idx_s[tid] = ai; is2_s[tid] = aj;
            if (a2 - a1 <= TAU) {
                if (a3 - a1 > TAU) { int p = atomicAdd(&pr_cnt, 1); pr_list[p] = tid; }
                else               { int p = atomicAdd(&rk_cnt, 1); rk_list[p] = tid; }
            }
        }
        __syncthreads();

        // ---- exact numpy-chain full recheck (very rare: m3 within TAU) ----
        {
            int ncheck = rk_cnt;
            for (int f = 0; f < ncheck; ++f) {
                int r = rk_list[f];
                if (tid < 64)
                    ((float4*)rrow_s)[tid] =
                        ((const float4*)(resd_g + (((size_t)(row0 + r)) << 8)))[tid];
                __syncthreads();
                float Sr = Srow[r];
                float accv[8];
                #pragma unroll
                for (int j = 0; j < 8; ++j) accv[j] = 0.f;
                const float* wp = Wk + ((size_t)tid * 8) * EDIM;
                for (int kb = 0; kb < 64; ++kb) {
                    float4 rv = *(const float4*)&rrow_s[kb * 4];
                    #pragma unroll
                    for (int j = 0; j < 8; ++j) {
                        float4 wv = *(const float4*)(wp + j * EDIM + kb * 4);
                        accv[j] = fmaf(rv.x, wv.x, accv[j]);
                        accv[j] = fmaf(rv.y, wv.y, accv[j]);
                        accv[j] = fmaf(rv.z, wv.z, accv[j]);
                        accv[j] = fmaf(rv.w, wv.w, accv[j]);
                    }
                }
                float bm = FLT_MAX; int bi = 0;
                #pragma unroll
                for (int j = 0; j < 8; ++j) {
                    int c = tid * 8 + j;
                    float d = fmaf(-2.0f, accv[j], Sr) + wsqk[c];
                    if (d < bm) { bm = d; bi = c; }
                }
                red_f[tid] = bm; red_i[tid] = bi;
                __syncthreads();
                for (int off = 128; off > 0; off >>= 1) {
                    if (tid < off) {
                        float v = red_f[tid + off]; int ii = red_i[tid + off];
                        if (v < red_f[tid] || (v == red_f[tid] && ii < red_i[tid])) {
                            red_f[tid] = v; red_i[tid] = ii;
                        }
                    }
                    __syncthreads();
                }
                if (tid == 0) idx_s[r] = red_i[0];
                __syncthreads();
            }
        }

        // ---- exact 2-candidate recheck (all threads; np-chain; tie -> lower idx) ----
        {
            int cnt2 = pr_cnt * 2;
            for (int base = 0; base < cnt2; base += NTHREADS) {
                int slot = base + tid;
                float d = FLT_MAX; int code = 0; int r = -1;
                if (slot < cnt2) {
                    r = pr_list[slot >> 1];
                    code = (slot & 1) ? is2_s[r] : idx_s[r];
                    const float* rp = resd_g + (((size_t)(row0 + r)) << 8);
                    const float* wp = Wk + ((size_t)code << 8);
                    float acc1 = 0.f;
                    for (int kb = 0; kb < 64; ++kb) {
                        float4 rv = *(const float4*)(rp + kb * 4);
                        float4 wv = *(const float4*)(wp + kb * 4);
                        acc1 = fmaf(rv.x, wv.x, acc1);
                        acc1 = fmaf(rv.y, wv.y, acc1);
                        acc1 = fmaf(rv.z, wv.z, acc1);
                        acc1 = fmaf(rv.w, wv.w, acc1);
                    }
                    d = fmaf(-2.0f, acc1, Srow[r]) + wsqk[code];
                }
                float dp = __shfl_xor(d, 1, 64);
                int   cp = __shfl_xor(code, 1, 64);
                if (slot < cnt2 && (slot & 1) == 0) {
                    idx_s[r] = (dp < d || (dp == d && cp < code)) ? cp : code;
                }
            }
        }
        __syncthreads();

        if (tid < TM)
            out[IDX_OFF + (size_t)(row0 + tid) * N_Q + q] = (float)idx_s[tid];
        __syncthreads();

        // ---- residual update (plain fp32 sub, numpy elementwise) + loss ----
        {
            const int d = tid;
            for (int r = 0; r < TM; ++r) {
                float w = Wk[(((size_t)idx_s[r]) << 8) + d];
                float* rp = resd_g + (((size_t)(row0 + r)) << 8) + d;
                float nv = *rp - w;
                *rp = nv;
                lsum = fmaf(nv, nv, lsum);
            }
        }
    }

    __syncthreads();
    // z_q = z - residual_final
    for (int i = tid; i < TM * 64; i += NTHREADS) {
        int r = i >> 6, c = i & 63;
        float4 zv = ((const float4*)z)[(((size_t)(row0 + r)) << 6) + c];
        float4 rv = ((const float4*)resd_g)[(((size_t)(row0 + r)) << 6) + c];
        float4 o = {zv.x - rv.x, zv.y - rv.y, zv.z - rv.z, zv.w - rv.w};
        ((float4*)out)[(((size_t)(row0 + r)) << 6) + c] = o;
    }
    #pragma unroll
    for (int off = 32; off > 0; off >>= 1) lsum += __shfl_down(lsum, off, 64);
    if (lane == 0) wavesum[wave] = lsum;
    __syncthreads();
    if (tid == 0)
        loss_partial[blockIdx.x] = wavesum[0] + wavesum[1] + wavesum[2] + wavesum[3];
}

__global__ __launch_bounds__(256) void loss_reduce(const float* __restrict__ partial,
                                                   float* __restrict__ out) {
    __shared__ float sh[256];
    int t = threadIdx.x;
    sh[t] = partial[t] + partial[t + 256];
    __syncthreads();
    for (int off = 128; off > 0; off >>= 1) {
        if (t < off) sh[t] += sh[t + off];
        __syncthreads();
    }
    if (t == 0)
        out[LOSS_OFF] = sh[0] * (1.25f / ((float)N_Q * (float)NROWS * (float)EDIM));
}

extern "C" void kernel_launch(void* const* d_in, const int* in_sizes, int n_in,
                              void* d_out, int out_size, void* d_ws, size_t ws_size,
                              hipStream_t stream) {
    const float* z = (const float*)d_in[0];   // [16,2048,256]
    const float* W = (const float*)d_in[1];   // [4,2048,256]
    float* out = (float*)d_out;

    // ws layout (bytes): wsq32 [0,32K) | partial [32K,34K) | wh [64K, 64K+4M) | resd [64K+8M, +32M)
    float* wsq32   = (float*)d_ws;
    float* partial = (float*)((char*)d_ws + 32768);
    short* wh      = (short*)((char*)d_ws + 65536);
    float* resd    = (float*)((char*)d_ws + 65536 + 8388608);

    hipLaunchKernelGGL(wsq_kernel, dim3(NE * N_Q / 4), dim3(NTHREADS), 0, stream, W, wsq32);
    hipLaunchKernelGGL(wh_kernel, dim3(1024), dim3(NTHREADS), 0, stream, W, wh);
    hipLaunchKernelGGL(rvq_main, dim3(NROWS / TM), dim3(NTHREADS), 0, stream,
                       z, W, wsq32, wh, resd, out, partial);
    hipLaunchKernelGGL(loss_reduce, dim3(1), dim3(NTHREADS), 0, stream, partial, out);
}